// Round 11
// baseline (1161.410 us; speedup 1.0000x reference)
//
#include <hip/hip_runtime.h>
#include <hip/hip_bf16.h>

#define Bc 4
#define Cc 128
#define Nn 4096

// ---------------------------------------------------------------------------
// K1: sq[b*N + n] = sum_c x[b][c][n]^2, sequential ascending FMA chain.
// MUST match k_gram_topk's per-acc chain bitwise so self-distance == 0.
// ---------------------------------------------------------------------------
__global__ void k_sq(const float* __restrict__ x, float* __restrict__ sq) {
    int id = blockIdx.x * 256 + threadIdx.x;          // 16384 total
    int b = id >> 12, n = id & (Nn - 1);
    const float* xb = x + (size_t)b * Cc * Nn + n;
    float a = 0.f;
    #pragma unroll 8
    for (int c = 0; c < Cc; ++c) {
        float v = xb[(size_t)c * Nn];
        a = fmaf(v, v, a);
    }
    sq[id] = a;
}

// ---------------------------------------------------------------------------
// sorted-ascending top-9 insert, fully unrolled (static register indexing).
// Strict < : on ties the EARLIER-inserted stays first.
// ---------------------------------------------------------------------------
__device__ __forceinline__ void insert9(float (&d)[9], int (&ix)[9], float nd, int ni) {
    float cx = nd; int cI = ni;
    #pragma unroll
    for (int p = 0; p < 9; ++p) {
        bool lt = cx < d[p];
        float td = d[p]; int ti = ix[p];
        if (lt) { d[p] = cx; ix[p] = cI; cx = td; cI = ti; }
    }
}

// Chunk swizzle: rotate within each 8-chunk run by run index.
// f(q) = (q&24) | ((q + (q>>3)) & 7). Bijective on 0..31. Staging writes
// conflict-free; compute reads <=2-way (free). Verified r10: conflicts
// 4.6e7 -> 1.68e7 (residual = 2-way reads).
__device__ __forceinline__ int swz(int q) { return (q & 24) | ((q + (q >> 3)) & 7); }

// ---------------------------------------------------------------------------
// K2 v7: Gram + per-row top-9, 8x8 register blocking, 32KB LDS.
// Round-10 finding: a 64KB block never co-schedules (occupancy pinned at
// 12% = 1 block/CU, 4 waves) -> ds_read->FMA latency fully exposed
// (VALUBusy 39%). v7 halves LDS to 32KB via channel-split 32: VGPR 168
// allows 3 waves/SIMD -> target 3 blocks/CU (12 waves, ~37% occupancy).
// Grid: 1024 = 4 batches x 32 row-groups x 8 column-eighths.
// Block: 128 rows x 512 cols (4 tiles of 128); tx=t&15 owns 8 cols,
// ty=t>>4 owns 8 rows -> 64 acc. LDS: A[32c][128r]+B[32c][128c] 16KB each;
// per tile 4 ch-stages (stage 32 channels, compute, repeat).
// Per-acc chain: one fmaf per channel, c = st*32+cl ascending == k_sq
// chain bitwise -> self-distance exactly 0. Cross-tx butterfly (v5 fix)
// merges the 16 column-slices per row before the single-writer store.
// ---------------------------------------------------------------------------
__global__ __launch_bounds__(256, 1) void k_gram_topk(
        const float* __restrict__ x, const float* __restrict__ sq,
        float* __restrict__ pd, int* __restrict__ pi) {
    __shared__ alignas(16) float As[32 * 128];   // 16KB
    __shared__ alignas(16) float Bs[32 * 128];   // 16KB
    float4* A4 = (float4*)As;
    float4* B4 = (float4*)Bs;

    const int t  = threadIdx.x;
    const int tx = t & 15;
    const int ty = t >> 4;
    const int bid = blockIdx.x;               // b*256 + rg*8 + oct
    const int b   = bid >> 8;
    const int rg  = (bid >> 3) & 31;
    const int oct = bid & 7;
    const int rowbase = rg * 128;
    const int coloct = oct * 512;
    const float* xb  = x + (size_t)b * Cc * Nn;
    const float* sqb = sq + b * Nn;

    float rown[8];
    #pragma unroll
    for (int i = 0; i < 8; ++i) rown[i] = sqb[rowbase + ty * 8 + i];

    float cd[8][9]; int ci[8][9];
    #pragma unroll
    for (int i = 0; i < 8; ++i)
        #pragma unroll
        for (int p = 0; p < 9; ++p) { cd[i][p] = 3.4e38f; ci[i][p] = 0; }

    const int ra0 = swz(ty * 2), ra1 = swz(ty * 2 + 1);
    const int rb0 = swz(tx * 2), rb1 = swz(tx * 2 + 1);

    for (int tile = 0; tile < 4; ++tile) {
        const int colbase = coloct + tile * 128;

        float acc[8][8];
        #pragma unroll
        for (int i = 0; i < 8; ++i)
            #pragma unroll
            for (int j = 0; j < 8; ++j) acc[i][j] = 0.f;

        #pragma unroll
        for (int st = 0; st < 4; ++st) {
            __syncthreads();                  // prior compute done
            #pragma unroll
            for (int j = 0; j < 4; ++j) {
                int idx = t + j * 256;        // 0..1023
                int cl = idx >> 5, q = idx & 31;
                const float* src = xb + (size_t)(st * 32 + cl) * Nn;
                A4[cl * 32 + swz(q)] = *(const float4*)&src[rowbase + q * 4];
                B4[cl * 32 + swz(q)] = *(const float4*)&src[colbase + q * 4];
            }
            __syncthreads();

            #pragma unroll 4
            for (int cl = 0; cl < 32; ++cl) {
                float4 a0 = A4[cl * 32 + ra0];    // rows ty*8+0..3
                float4 a1 = A4[cl * 32 + ra1];    // rows ty*8+4..7
                float4 b0 = B4[cl * 32 + rb0];    // cols tx*8+0..3
                float4 b1 = B4[cl * 32 + rb1];    // cols tx*8+4..7
                float av[8] = {a0.x, a0.y, a0.z, a0.w, a1.x, a1.y, a1.z, a1.w};
                float bv[8] = {b0.x, b0.y, b0.z, b0.w, b1.x, b1.y, b1.z, b1.w};
                #pragma unroll
                for (int i = 0; i < 8; ++i)
                    #pragma unroll
                    for (int j = 0; j < 8; ++j)
                        acc[i][j] = fmaf(av[i], bv[j], acc[i][j]); // c-ascending
            }
        }

        float4 cn0 = *(const float4*)&sqb[colbase + tx * 8];
        float4 cn1 = *(const float4*)&sqb[colbase + tx * 8 + 4];
        float cn[8] = {cn0.x, cn0.y, cn0.z, cn0.w, cn1.x, cn1.y, cn1.z, cn1.w};
        #pragma unroll
        for (int i = 0; i < 8; ++i)
            #pragma unroll
            for (int j = 0; j < 8; ++j) {
                float d2 = fmaf(-2.0f, acc[i][j], rown[i] + cn[j]);
                if (d2 < cd[i][8]) insert9(cd[i], ci[i], d2, colbase + tx * 8 + j);
            }
    }

    // cross-tx merge: the 16 lanes sharing ty hold disjoint column slices of
    // the same 8 rows. Butterfly over tx bits (consecutive lanes, one wave).
    #pragma unroll
    for (int m = 1; m < 16; m <<= 1) {
        #pragma unroll
        for (int i = 0; i < 8; ++i) {
            float od[9]; int oi[9];
            #pragma unroll
            for (int p = 0; p < 9; ++p) {
                od[p] = __shfl_xor(cd[i][p], m);
                oi[p] = __shfl_xor(ci[i][p], m);
            }
            #pragma unroll
            for (int p = 0; p < 9; ++p)
                if (od[p] < cd[i][8]) insert9(cd[i], ci[i], od[p], oi[p]);
        }
    }

    // partial lists: pd/pi[b][oct][k][n], single writer per row (tx==0)
    if (tx == 0) {
        #pragma unroll
        for (int i = 0; i < 8; ++i) {
            int n = rowbase + ty * 8 + i;
            #pragma unroll
            for (int k = 0; k < 9; ++k) {
                size_t o = (((size_t)b * 8 + oct) * 9 + k) * Nn + n;
                pd[o] = cd[i][k];
                pi[o] = ci[i][k];
            }
        }
    }
}

// ---------------------------------------------------------------------------
// K2b: merge the eight column-octant top-9 lists per row. Ascending octant
// order + strict-< insertion keeps lower col indices first on ties (stable).
// ---------------------------------------------------------------------------
__global__ void k_merge(const float* __restrict__ pd, const int* __restrict__ pi,
                        int* __restrict__ idxOut) {
    int id = blockIdx.x * 256 + threadIdx.x;  // 16384
    int b = id >> 12, n = id & (Nn - 1);
    float d0[9]; int i0[9];
    #pragma unroll
    for (int k = 0; k < 9; ++k) {
        size_t o = (((size_t)b * 8 + 0) * 9 + k) * Nn + n;
        d0[k] = pd[o]; i0[k] = pi[o];
    }
    #pragma unroll
    for (int q = 1; q < 8; ++q) {
        #pragma unroll
        for (int k = 0; k < 9; ++k) {
            size_t o = (((size_t)b * 8 + q) * 9 + k) * Nn + n;
            float dv = pd[o]; int iv = pi[o];
            if (dv < d0[8]) insert9(d0, i0, dv, iv);
        }
    }
    #pragma unroll
    for (int k = 0; k < 9; ++k)
        idxOut[((size_t)b * 9 + k) * Nn + n] = i0[k];
}

// ---------------------------------------------------------------------------
// K3: h0[b][c][n] = (1+eps)*x[b][c][n] + sum_k x[b][c][idx[b][k][n]]
// ---------------------------------------------------------------------------
__global__ void k_gather(const float* __restrict__ x, const int* __restrict__ idx,
                         const float* __restrict__ epsp, float* __restrict__ h0) {
    int id = blockIdx.x * 256 + threadIdx.x;          // B*C*N = 2097152
    int n  = id & (Nn - 1);
    int bc = id >> 12;                                // b*C + c
    int b  = bc >> 7;
    const float* xr = x + (size_t)bc * Nn;
    const int* ib = idx + (size_t)b * 9 * Nn + n;
    float s = (1.0f + epsp[0]) * xr[n];
    #pragma unroll
    for (int k = 0; k < 9; ++k) s += xr[ib[(size_t)k * Nn]];
    h0[id] = s;
}

// ---------------------------------------------------------------------------
// K4/K5: out[b][d][n] = act( bias[d] + sum_c W[c][d] * in[b][c][n] )
// ---------------------------------------------------------------------------
template <bool RELU>
__global__ __launch_bounds__(256, 2) void k_mlp(
        const float* __restrict__ in, const float* __restrict__ W,
        const float* __restrict__ bias, float* __restrict__ out) {
    const int t  = threadIdx.x;
    const int td = t & 15;
    const int tn = t >> 4;
    const int bid = blockIdx.x;   // B*2*64 = 512
    const int b = bid >> 7;
    const int dbase = ((bid >> 6) & 1) * 64;
    const int nb = (bid & 63) * 64;

    __shared__ alignas(16) float Ws[128 * 64];
    __shared__ alignas(16) float Hs[128 * 64];

    for (int k = t; k < 128 * 64; k += 256) {
        int i = k & 63; int c = k >> 6;
        int sw = c * 64 + ((((i >> 2) ^ (c & 7)) << 2) | (i & 3));
        Ws[sw] = W[c * 128 + dbase + i];
        Hs[sw] = in[((size_t)b * 128 + c) * Nn + nb + i];
    }
    __syncthreads();

    float acc[4][4];
    #pragma unroll
    for (int dd = 0; dd < 4; ++dd)
        #pragma unroll
        for (int nn = 0; nn < 4; ++nn) acc[dd][nn] = 0.f;

    const float4* W4 = reinterpret_cast<const float4*>(Ws);
    const float4* H4 = reinterpret_cast<const float4*>(Hs);
    for (int c = 0; c < 128; ++c) {
        int cx = c & 7;
        float4 w = W4[c * 16 + (td ^ cx)];
        float4 h = H4[c * 16 + (tn ^ cx)];
        float wf[4] = {w.x, w.y, w.z, w.w};
        float hf[4] = {h.x, h.y, h.z, h.w};
        #pragma unroll
        for (int dd = 0; dd < 4; ++dd)
            #pragma unroll
            for (int nn = 0; nn < 4; ++nn)
                acc[dd][nn] = fmaf(wf[dd], hf[nn], acc[dd][nn]);
    }

    #pragma unroll
    for (int dd = 0; dd < 4; ++dd) {
        int d = dbase + 4 * td + dd;
        float bb = bias[d];
        float4 o;
        o.x = acc[dd][0] + bb; o.y = acc[dd][1] + bb;
        o.z = acc[dd][2] + bb; o.w = acc[dd][3] + bb;
        if (RELU) {
            o.x = fmaxf(o.x, 0.f); o.y = fmaxf(o.y, 0.f);
            o.z = fmaxf(o.z, 0.f); o.w = fmaxf(o.w, 0.f);
        }
        *reinterpret_cast<float4*>(&out[((size_t)b * 128 + d) * Nn + nb + 4 * tn]) = o;
    }
}

// ---------------------------------------------------------------------------
// K6: per-channel batch-norm stats (biased var), 1 block per channel.
// ---------------------------------------------------------------------------
__global__ void k_bnstats(const float* __restrict__ o, const float* __restrict__ gamma,
                          const float* __restrict__ beta, float* __restrict__ scsh) {
    int e = blockIdx.x, t = threadIdx.x;
    float s = 0.f, s2 = 0.f;
    for (int b = 0; b < Bc; ++b) {
        const float* p = o + ((size_t)b * 128 + e) * Nn;
        for (int n = t; n < Nn; n += 256) {
            float v = p[n];
            s += v;
            s2 = fmaf(v, v, s2);
        }
    }
    __shared__ float rs[256], rq[256];
    rs[t] = s; rq[t] = s2;
    __syncthreads();
    for (int off = 128; off > 0; off >>= 1) {
        if (t < off) { rs[t] += rs[t + off]; rq[t] += rq[t + off]; }
        __syncthreads();
    }
    if (t == 0) {
        float mean = rs[0] * (1.0f / 16384.0f);
        float var  = rq[0] * (1.0f / 16384.0f) - mean * mean;
        if (var < 0.f) var = 0.f;
        float sc = gamma[e] * rsqrtf(var + 1e-5f);
        scsh[e] = sc;
        scsh[128 + e] = beta[e] - mean * sc;
    }
}

// ---------------------------------------------------------------------------
// K7: out = relu(scale[e]*o + shift[e] + x), in place on d_out, float4.
// ---------------------------------------------------------------------------
__global__ void k_bnapply(float* __restrict__ o, const float* __restrict__ x,
                          const float* __restrict__ scsh) {
    int id4 = blockIdx.x * 256 + threadIdx.x;         // 524288
    int e = (id4 >> 10) & 127;
    float sc = scsh[e], sh = scsh[128 + e];
    float4 v = reinterpret_cast<const float4*>(o)[id4];
    float4 r = reinterpret_cast<const float4*>(x)[id4];
    float4 w;
    w.x = fmaxf(fmaf(sc, v.x, sh) + r.x, 0.f);
    w.y = fmaxf(fmaf(sc, v.y, sh) + r.y, 0.f);
    w.z = fmaxf(fmaf(sc, v.z, sh) + r.z, 0.f);
    w.w = fmaxf(fmaf(sc, v.w, sh) + r.w, 0.f);
    reinterpret_cast<float4*>(o)[id4] = w;
}

// ---------------------------------------------------------------------------
extern "C" void kernel_launch(void* const* d_in, const int* in_sizes, int n_in,
                              void* d_out, int out_size, void* d_ws, size_t ws_size,
                              hipStream_t stream) {
    const float* x     = (const float*)d_in[0];
    const float* epsp  = (const float*)d_in[1];
    const float* W1    = (const float*)d_in[2];
    const float* b1    = (const float*)d_in[3];
    const float* W2    = (const float*)d_in[4];
    const float* b2    = (const float*)d_in[5];
    const float* gamma = (const float*)d_in[6];
    const float* beta  = (const float*)d_in[7];
    float* out = (float*)d_out;

    // workspace (floats): sq[16384] | idx[147456] | h0[2097152] | h1[2097152]
    // | scsh[256]  (~17.4 MB). pd aliases h0, pi aliases h1 (each
    // [4][8][9][4096] = 1179648 elems <= 2097152): both consumed by k_merge
    // BEFORE k_gather writes h0 and k_mlp<true> writes h1.
    float* ws   = (float*)d_ws;
    float* sq   = ws;
    int*   idx  = (int*)(ws + 16384);
    float* h0   = ws + 16384 + (size_t)Bc * 9 * Nn;
    float* h1   = h0 + (size_t)Bc * Cc * Nn;
    float* scsh = h1 + (size_t)Bc * Cc * Nn;
    float* pd   = h0;                          // [4][8][9][4096]
    int*   pi   = (int*)h1;                    // [4][8][9][4096]

    k_sq        <<<64,   256, 0, stream>>>(x, sq);
    k_gram_topk <<<1024, 256, 0, stream>>>(x, sq, pd, pi);
    k_merge     <<<64,   256, 0, stream>>>(pd, pi, idx);
    k_gather    <<<8192, 256, 0, stream>>>(x, idx, epsp, h0);
    k_mlp<true> <<<512,  256, 0, stream>>>(h0, W1, b1, h1);
    k_mlp<false><<<512,  256, 0, stream>>>(h1, W2, b2, out);
    k_bnstats   <<<128,  256, 0, stream>>>(out, gamma, beta, scsh);
    k_bnapply   <<<2048, 256, 0, stream>>>(out, x, scsh);
}

// Round 12
// 716.412 us; speedup vs baseline: 1.6211x; 1.6211x over previous
//
#include <hip/hip_runtime.h>
#include <hip/hip_bf16.h>

#define Bc 4
#define Cc 128
#define Nn 4096

// ---------------------------------------------------------------------------
// K1: sq[b*N + n] = sum_c x[b][c][n]^2, sequential ascending FMA chain.
// MUST match k_gram_topk's per-acc chain bitwise so self-distance == 0.
// ---------------------------------------------------------------------------
__global__ void k_sq(const float* __restrict__ x, float* __restrict__ sq) {
    int id = blockIdx.x * 256 + threadIdx.x;          // 16384 total
    int b = id >> 12, n = id & (Nn - 1);
    const float* xb = x + (size_t)b * Cc * Nn + n;
    float a = 0.f;
    #pragma unroll 8
    for (int c = 0; c < Cc; ++c) {
        float v = xb[(size_t)c * Nn];
        a = fmaf(v, v, a);
    }
    sq[id] = a;
}

// ---------------------------------------------------------------------------
// sorted-ascending top-9 insert, fully unrolled (static register indexing).
// Strict < : on ties the EARLIER-inserted stays first.
// ---------------------------------------------------------------------------
__device__ __forceinline__ void insert9(float (&d)[9], int (&ix)[9], float nd, int ni) {
    float cx = nd; int cI = ni;
    #pragma unroll
    for (int p = 0; p < 9; ++p) {
        bool lt = cx < d[p];
        float td = d[p]; int ti = ix[p];
        if (lt) { d[p] = cx; ix[p] = cI; cx = td; cI = ti; }
    }
}

// Chunk swizzles: rotate within each 8-chunk run by run index. Bijective.
// Staging writes conflict-free; compute reads <=2-way (free, m136).
__device__ __forceinline__ int swz(int q)   { return (q & 24) | ((q + (q >> 3)) & 7); }
__device__ __forceinline__ int swz16(int q) { return (q & 8)  | ((q + (q >> 3)) & 7); }

// ---------------------------------------------------------------------------
// K2 v9: Gram + per-row top-9, 4x8 register blocking, 24KB LDS, <=128 VGPR.
// EVIDENCE r8/r10/r11: occupancy pinned at 12.5% (1 wave/SIMD) across LDS
// 64KB and 32KB; r1 showed launch_bounds(256,2) caps VGPR at exactly 128
// => effective per-SIMD VGPR pool ~256. Our 176-VGPR kernel could never
// get a 2nd wave per SIMD. v9 halves the register hog (top-9 lists):
// 4 rows x 8 cols per thread -> lists 72 + acc 32 ~= 115 VGPR target.
// Grid: 2048 = 4 batches x 64 row-groups (64 rows) x 8 column-octants.
// Block: 64 rows x 512 cols (4 tiles of 128); tx=t&15 owns 8 cols,
// ty=t>>4 owns 4 rows. LDS: A[32c][64r] 8KB + B[32c][128c] 16KB; per tile
// 4 ch-stages. A-read is one b128 broadcast across the 16 tx-lanes (free).
// Per-acc chain: one fmaf per channel, c = st*32+cl ascending == k_sq
// chain bitwise -> self-distance exactly 0. Cross-tx butterfly merges the
// 16 column-slices per row before the single-writer store.
// ---------------------------------------------------------------------------
__global__ __launch_bounds__(256, 1) void k_gram_topk(
        const float* __restrict__ x, const float* __restrict__ sq,
        float* __restrict__ pd, int* __restrict__ pi) {
    __shared__ alignas(16) float As[32 * 64];    // 8KB
    __shared__ alignas(16) float Bs[32 * 128];   // 16KB
    float4* A4 = (float4*)As;
    float4* B4 = (float4*)Bs;

    const int t  = threadIdx.x;
    const int tx = t & 15;
    const int ty = t >> 4;
    const int bid = blockIdx.x;               // (b*64 + rg)*8 + oct
    const int b   = bid >> 9;
    const int rg  = (bid >> 3) & 63;
    const int oct = bid & 7;
    const int rowbase = rg * 64;
    const int coloct = oct * 512;
    const float* xb  = x + (size_t)b * Cc * Nn;
    const float* sqb = sq + b * Nn;

    float rown[4];
    #pragma unroll
    for (int i = 0; i < 4; ++i) rown[i] = sqb[rowbase + ty * 4 + i];

    float cd[4][9]; int ci[4][9];
    #pragma unroll
    for (int i = 0; i < 4; ++i)
        #pragma unroll
        for (int p = 0; p < 9; ++p) { cd[i][p] = 3.4e38f; ci[i][p] = 0; }

    const int ra  = swz16(ty);                // rows ty*4..ty*4+3, broadcast
    const int rb0 = swz(tx * 2), rb1 = swz(tx * 2 + 1);

    for (int tile = 0; tile < 4; ++tile) {
        const int colbase = coloct + tile * 128;

        float acc[4][8];
        #pragma unroll
        for (int i = 0; i < 4; ++i)
            #pragma unroll
            for (int j = 0; j < 8; ++j) acc[i][j] = 0.f;

        #pragma unroll
        for (int st = 0; st < 4; ++st) {
            const int c0 = st * 32;
            __syncthreads();                  // prior compute done
            // stage A: 512 float4 (32 cl x 16 chunks)
            #pragma unroll
            for (int j = 0; j < 2; ++j) {
                int i = t + j * 256;
                int cl = i >> 4, q = i & 15;
                A4[cl * 16 + swz16(q)] =
                    *(const float4*)&xb[(size_t)(c0 + cl) * Nn + rowbase + q * 4];
            }
            // stage B: 1024 float4 (32 cl x 32 chunks)
            #pragma unroll
            for (int j = 0; j < 4; ++j) {
                int i = t + j * 256;
                int cl = i >> 5, q = i & 31;
                B4[cl * 32 + swz(q)] =
                    *(const float4*)&xb[(size_t)(c0 + cl) * Nn + colbase + q * 4];
            }
            __syncthreads();

            #pragma unroll 4
            for (int cl = 0; cl < 32; ++cl) {
                float4 a  = A4[cl * 16 + ra];     // rows ty*4+0..3 (broadcast)
                float4 b0 = B4[cl * 32 + rb0];    // cols tx*8+0..3
                float4 b1 = B4[cl * 32 + rb1];    // cols tx*8+4..7
                float av[4] = {a.x, a.y, a.z, a.w};
                float bv[8] = {b0.x, b0.y, b0.z, b0.w, b1.x, b1.y, b1.z, b1.w};
                #pragma unroll
                for (int i = 0; i < 4; ++i)
                    #pragma unroll
                    for (int j = 0; j < 8; ++j)
                        acc[i][j] = fmaf(av[i], bv[j], acc[i][j]); // c-ascending
            }
        }

        float4 cn0 = *(const float4*)&sqb[colbase + tx * 8];
        float4 cn1 = *(const float4*)&sqb[colbase + tx * 8 + 4];
        float cn[8] = {cn0.x, cn0.y, cn0.z, cn0.w, cn1.x, cn1.y, cn1.z, cn1.w};
        #pragma unroll
        for (int i = 0; i < 4; ++i)
            #pragma unroll
            for (int j = 0; j < 8; ++j) {
                float d2 = fmaf(-2.0f, acc[i][j], rown[i] + cn[j]);
                if (d2 < cd[i][8]) insert9(cd[i], ci[i], d2, colbase + tx * 8 + j);
            }
    }

    // cross-tx merge: the 16 lanes sharing ty hold disjoint column slices of
    // the same 4 rows. Butterfly over tx bits (consecutive lanes, one wave).
    #pragma unroll
    for (int m = 1; m < 16; m <<= 1) {
        #pragma unroll
        for (int i = 0; i < 4; ++i) {
            float od[9]; int oi[9];
            #pragma unroll
            for (int p = 0; p < 9; ++p) {
                od[p] = __shfl_xor(cd[i][p], m);
                oi[p] = __shfl_xor(ci[i][p], m);
            }
            #pragma unroll
            for (int p = 0; p < 9; ++p)
                if (od[p] < cd[i][8]) insert9(cd[i], ci[i], od[p], oi[p]);
        }
    }

    // partial lists: pd/pi[b][oct][k][n], single writer per row (tx==0)
    if (tx == 0) {
        #pragma unroll
        for (int i = 0; i < 4; ++i) {
            int n = rowbase + ty * 4 + i;
            #pragma unroll
            for (int k = 0; k < 9; ++k) {
                size_t o = (((size_t)b * 8 + oct) * 9 + k) * Nn + n;
                pd[o] = cd[i][k];
                pi[o] = ci[i][k];
            }
        }
    }
}

// ---------------------------------------------------------------------------
// K2b: merge the eight column-octant top-9 lists per row. Ascending octant
// order + strict-< insertion keeps lower col indices first on ties (stable).
// ---------------------------------------------------------------------------
__global__ void k_merge(const float* __restrict__ pd, const int* __restrict__ pi,
                        int* __restrict__ idxOut) {
    int id = blockIdx.x * 256 + threadIdx.x;  // 16384
    int b = id >> 12, n = id & (Nn - 1);
    float d0[9]; int i0[9];
    #pragma unroll
    for (int k = 0; k < 9; ++k) {
        size_t o = (((size_t)b * 8 + 0) * 9 + k) * Nn + n;
        d0[k] = pd[o]; i0[k] = pi[o];
    }
    #pragma unroll
    for (int q = 1; q < 8; ++q) {
        #pragma unroll
        for (int k = 0; k < 9; ++k) {
            size_t o = (((size_t)b * 8 + q) * 9 + k) * Nn + n;
            float dv = pd[o]; int iv = pi[o];
            if (dv < d0[8]) insert9(d0, i0, dv, iv);
        }
    }
    #pragma unroll
    for (int k = 0; k < 9; ++k)
        idxOut[((size_t)b * 9 + k) * Nn + n] = i0[k];
}

// ---------------------------------------------------------------------------
// K3: h0[b][c][n] = (1+eps)*x[b][c][n] + sum_k x[b][c][idx[b][k][n]]
// ---------------------------------------------------------------------------
__global__ void k_gather(const float* __restrict__ x, const int* __restrict__ idx,
                         const float* __restrict__ epsp, float* __restrict__ h0) {
    int id = blockIdx.x * 256 + threadIdx.x;          // B*C*N = 2097152
    int n  = id & (Nn - 1);
    int bc = id >> 12;                                // b*C + c
    int b  = bc >> 7;
    const float* xr = x + (size_t)bc * Nn;
    const int* ib = idx + (size_t)b * 9 * Nn + n;
    float s = (1.0f + epsp[0]) * xr[n];
    #pragma unroll
    for (int k = 0; k < 9; ++k) s += xr[ib[(size_t)k * Nn]];
    h0[id] = s;
}

// ---------------------------------------------------------------------------
// K4/K5: out[b][d][n] = act( bias[d] + sum_c W[c][d] * in[b][c][n] )
// ---------------------------------------------------------------------------
template <bool RELU>
__global__ __launch_bounds__(256, 2) void k_mlp(
        const float* __restrict__ in, const float* __restrict__ W,
        const float* __restrict__ bias, float* __restrict__ out) {
    const int t  = threadIdx.x;
    const int td = t & 15;
    const int tn = t >> 4;
    const int bid = blockIdx.x;   // B*2*64 = 512
    const int b = bid >> 7;
    const int dbase = ((bid >> 6) & 1) * 64;
    const int nb = (bid & 63) * 64;

    __shared__ alignas(16) float Ws[128 * 64];
    __shared__ alignas(16) float Hs[128 * 64];

    for (int k = t; k < 128 * 64; k += 256) {
        int i = k & 63; int c = k >> 6;
        int sw = c * 64 + ((((i >> 2) ^ (c & 7)) << 2) | (i & 3));
        Ws[sw] = W[c * 128 + dbase + i];
        Hs[sw] = in[((size_t)b * 128 + c) * Nn + nb + i];
    }
    __syncthreads();

    float acc[4][4];
    #pragma unroll
    for (int dd = 0; dd < 4; ++dd)
        #pragma unroll
        for (int nn = 0; nn < 4; ++nn) acc[dd][nn] = 0.f;

    const float4* W4 = reinterpret_cast<const float4*>(Ws);
    const float4* H4 = reinterpret_cast<const float4*>(Hs);
    for (int c = 0; c < 128; ++c) {
        int cx = c & 7;
        float4 w = W4[c * 16 + (td ^ cx)];
        float4 h = H4[c * 16 + (tn ^ cx)];
        float wf[4] = {w.x, w.y, w.z, w.w};
        float hf[4] = {h.x, h.y, h.z, h.w};
        #pragma unroll
        for (int dd = 0; dd < 4; ++dd)
            #pragma unroll
            for (int nn = 0; nn < 4; ++nn)
                acc[dd][nn] = fmaf(wf[dd], hf[nn], acc[dd][nn]);
    }

    #pragma unroll
    for (int dd = 0; dd < 4; ++dd) {
        int d = dbase + 4 * td + dd;
        float bb = bias[d];
        float4 o;
        o.x = acc[dd][0] + bb; o.y = acc[dd][1] + bb;
        o.z = acc[dd][2] + bb; o.w = acc[dd][3] + bb;
        if (RELU) {
            o.x = fmaxf(o.x, 0.f); o.y = fmaxf(o.y, 0.f);
            o.z = fmaxf(o.z, 0.f); o.w = fmaxf(o.w, 0.f);
        }
        *reinterpret_cast<float4*>(&out[((size_t)b * 128 + d) * Nn + nb + 4 * tn]) = o;
    }
}

// ---------------------------------------------------------------------------
// K6: per-channel batch-norm stats (biased var), 1 block per channel.
// ---------------------------------------------------------------------------
__global__ void k_bnstats(const float* __restrict__ o, const float* __restrict__ gamma,
                          const float* __restrict__ beta, float* __restrict__ scsh) {
    int e = blockIdx.x, t = threadIdx.x;
    float s = 0.f, s2 = 0.f;
    for (int b = 0; b < Bc; ++b) {
        const float* p = o + ((size_t)b * 128 + e) * Nn;
        for (int n = t; n < Nn; n += 256) {
            float v = p[n];
            s += v;
            s2 = fmaf(v, v, s2);
        }
    }
    __shared__ float rs[256], rq[256];
    rs[t] = s; rq[t] = s2;
    __syncthreads();
    for (int off = 128; off > 0; off >>= 1) {
        if (t < off) { rs[t] += rs[t + off]; rq[t] += rq[t + off]; }
        __syncthreads();
    }
    if (t == 0) {
        float mean = rs[0] * (1.0f / 16384.0f);
        float var  = rq[0] * (1.0f / 16384.0f) - mean * mean;
        if (var < 0.f) var = 0.f;
        float sc = gamma[e] * rsqrtf(var + 1e-5f);
        scsh[e] = sc;
        scsh[128 + e] = beta[e] - mean * sc;
    }
}

// ---------------------------------------------------------------------------
// K7: out = relu(scale[e]*o + shift[e] + x), in place on d_out, float4.
// ---------------------------------------------------------------------------
__global__ void k_bnapply(float* __restrict__ o, const float* __restrict__ x,
                          const float* __restrict__ scsh) {
    int id4 = blockIdx.x * 256 + threadIdx.x;         // 524288
    int e = (id4 >> 10) & 127;
    float sc = scsh[e], sh = scsh[128 + e];
    float4 v = reinterpret_cast<const float4*>(o)[id4];
    float4 r = reinterpret_cast<const float4*>(x)[id4];
    float4 w;
    w.x = fmaxf(fmaf(sc, v.x, sh) + r.x, 0.f);
    w.y = fmaxf(fmaf(sc, v.y, sh) + r.y, 0.f);
    w.z = fmaxf(fmaf(sc, v.z, sh) + r.z, 0.f);
    w.w = fmaxf(fmaf(sc, v.w, sh) + r.w, 0.f);
    reinterpret_cast<float4*>(o)[id4] = w;
}

// ---------------------------------------------------------------------------
extern "C" void kernel_launch(void* const* d_in, const int* in_sizes, int n_in,
                              void* d_out, int out_size, void* d_ws, size_t ws_size,
                              hipStream_t stream) {
    const float* x     = (const float*)d_in[0];
    const float* epsp  = (const float*)d_in[1];
    const float* W1    = (const float*)d_in[2];
    const float* b1    = (const float*)d_in[3];
    const float* W2    = (const float*)d_in[4];
    const float* b2    = (const float*)d_in[5];
    const float* gamma = (const float*)d_in[6];
    const float* beta  = (const float*)d_in[7];
    float* out = (float*)d_out;

    // workspace (floats): sq[16384] | idx[147456] | h0[2097152] | h1[2097152]
    // | scsh[256]  (~17.4 MB). pd aliases h0, pi aliases h1 (each
    // [4][8][9][4096] = 1179648 elems <= 2097152): both consumed by k_merge
    // BEFORE k_gather writes h0 and k_mlp<true> writes h1.
    float* ws   = (float*)d_ws;
    float* sq   = ws;
    int*   idx  = (int*)(ws + 16384);
    float* h0   = ws + 16384 + (size_t)Bc * 9 * Nn;
    float* h1   = h0 + (size_t)Bc * Cc * Nn;
    float* scsh = h1 + (size_t)Bc * Cc * Nn;
    float* pd   = h0;                          // [4][8][9][4096]
    int*   pi   = (int*)h1;                    // [4][8][9][4096]

    k_sq        <<<64,   256, 0, stream>>>(x, sq);
    k_gram_topk <<<2048, 256, 0, stream>>>(x, sq, pd, pi);
    k_merge     <<<64,   256, 0, stream>>>(pd, pi, idx);
    k_gather    <<<8192, 256, 0, stream>>>(x, idx, epsp, h0);
    k_mlp<true> <<<512,  256, 0, stream>>>(h0, W1, b1, h1);
    k_mlp<false><<<512,  256, 0, stream>>>(h1, W2, b2, out);
    k_bnstats   <<<128,  256, 0, stream>>>(out, gamma, beta, scsh);
    k_bnapply   <<<2048, 256, 0, stream>>>(out, x, scsh);
}

// Round 13
// 629.006 us; speedup vs baseline: 1.8464x; 1.1390x over previous
//
#include <hip/hip_runtime.h>
#include <hip/hip_bf16.h>

#define Bc 4
#define Cc 128
#define Nn 4096

// ---------------------------------------------------------------------------
// K1: sq[b*N + n] = sum_c x[b][c][n]^2, sequential ascending FMA chain.
// MUST match k_gram_topk's per-acc chain bitwise so self-distance == 0.
// ---------------------------------------------------------------------------
__global__ void k_sq(const float* __restrict__ x, float* __restrict__ sq) {
    int id = blockIdx.x * 256 + threadIdx.x;          // 16384 total
    int b = id >> 12, n = id & (Nn - 1);
    const float* xb = x + (size_t)b * Cc * Nn + n;
    float a = 0.f;
    #pragma unroll 8
    for (int c = 0; c < Cc; ++c) {
        float v = xb[(size_t)c * Nn];
        a = fmaf(v, v, a);
    }
    sq[id] = a;
}

// ---------------------------------------------------------------------------
// sorted-ascending top-9 insert, fully unrolled (static register indexing).
// Strict < : on ties the EARLIER-inserted stays first.
// ---------------------------------------------------------------------------
__device__ __forceinline__ void insert9(float (&d)[9], int (&ix)[9], float nd, int ni) {
    float cx = nd; int cI = ni;
    #pragma unroll
    for (int p = 0; p < 9; ++p) {
        bool lt = cx < d[p];
        float td = d[p]; int ti = ix[p];
        if (lt) { d[p] = cx; ix[p] = cI; cx = td; cI = ti; }
    }
}

// Chunk swizzles (rotate within each 8-chunk run by run index) + inverses.
// LDS layout identical to r12; with global_load_lds the LDS write is linear
// (wave base + lane*16), so the SOURCE global chunk is inverse-swizzled
// instead (m173 pattern). Compute reads unchanged: <=2-way (free-ish).
__device__ __forceinline__ int swz(int q)    { return (q & 24) | ((q + (q >> 3)) & 7); }
__device__ __forceinline__ int swz16(int q)  { return (q & 8)  | ((q + (q >> 3)) & 7); }

// global -> LDS direct 16B async copy (no VGPR round-trip, counted by vmcnt;
// __syncthreads() drains vmcnt before s_barrier -> data visible after sync)
__device__ __forceinline__ void gload16(const float* g, float* l) {
    __builtin_amdgcn_global_load_lds(
        (const __attribute__((address_space(1))) void*)g,
        (__attribute__((address_space(3))) void*)l, 16, 0, 0);
}

// ---------------------------------------------------------------------------
// K2 v10: Gram + per-row top-9, 4x8 blocking, DOUBLE-BUFFERED LDS (48KB)
// with global_load_lds staging.
// r12 confirmed the ~256-VGPR/SIMD pool: VGPR 108 -> 2 waves/SIMD (23% occ),
// 595us. Remaining gap vs ~220us pipe floor = staging latency exposed every
// stage (load->barrier->compute serial) + 32 barriers. v10: per stage,
// sync -> issue next stage's 6 gload_lds into buf^1 -> compute buf. Load
// latency hides under ~2000cyc compute; 16 barriers; staging uses no VGPRs.
// Grid: 2048 = 4 b x 64 row-groups (64 rows) x 8 col-octants (512 cols).
// 16 linear stages = 4 tiles x 4 ch-stages. tx owns 8 cols, ty owns 4 rows.
// Per-acc chain: one fmaf per channel, c ascending == k_sq chain bitwise
// -> self-distance exactly 0. Cross-tx butterfly + single-writer store.
// ---------------------------------------------------------------------------
__global__ __launch_bounds__(256, 1) void k_gram_topk(
        const float* __restrict__ x, const float* __restrict__ sq,
        float* __restrict__ pd, int* __restrict__ pi) {
    __shared__ alignas(16) float As[2][32 * 64];    // 2 x 8KB
    __shared__ alignas(16) float Bs[2][32 * 128];   // 2 x 16KB

    const int t  = threadIdx.x;
    const int tx = t & 15;
    const int ty = t >> 4;
    const int bid = blockIdx.x;               // (b*64 + rg)*8 + oct
    const int b   = bid >> 9;
    const int rg  = (bid >> 3) & 63;
    const int oct = bid & 7;
    const int rowbase = rg * 64;
    const int coloct = oct * 512;
    const float* xb  = x + (size_t)b * Cc * Nn;
    const float* sqb = sq + b * Nn;

    float rown[4];
    #pragma unroll
    for (int i = 0; i < 4; ++i) rown[i] = sqb[rowbase + ty * 4 + i];

    float cd[4][9]; int ci[4][9];
    #pragma unroll
    for (int i = 0; i < 4; ++i)
        #pragma unroll
        for (int p = 0; p < 9; ++p) { cd[i][p] = 3.4e38f; ci[i][p] = 0; }

    const int ra  = swz16(ty);                // rows ty*4..ty*4+3 (broadcast)
    const int rb0 = swz(tx * 2), rb1 = swz(tx * 2 + 1);

    // issue one stage's loads: s = tile*4 + st; LDS dest linear, source
    // chunk inverse-swizzled so global chunk q lands at LDS slot swz(q).
    auto STAGE = [&](int s, int buf) {
        const int c0 = (s & 3) * 32;
        const int colbase = coloct + (s >> 2) * 128;
        float* Ab = &As[buf][0];
        float* Bb = &Bs[buf][0];
        #pragma unroll
        for (int j = 0; j < 2; ++j) {         // A: 512 float4
            int f = j * 256 + t;
            int cl = f >> 4, q = f & 15;
            int qi = (q & 8) | ((q - (q >> 3)) & 7);   // inv of swz16
            gload16(&xb[(size_t)(c0 + cl) * Nn + rowbase + qi * 4],
                    &Ab[(f & ~63) * 4]);
        }
        #pragma unroll
        for (int j = 0; j < 4; ++j) {         // B: 1024 float4
            int f = j * 256 + t;
            int cl = f >> 5, q = f & 31;
            int qi = (q & 24) | ((q - (q >> 3)) & 7);  // inv of swz
            gload16(&xb[(size_t)(c0 + cl) * Nn + colbase + qi * 4],
                    &Bb[(f & ~63) * 4]);
        }
    };

    STAGE(0, 0);

    float acc[4][8];
    for (int s = 0; s < 16; ++s) {
        const int buf = s & 1;
        __syncthreads();          // drains vmcnt -> buf's data landed; syncs
        if (s < 15) STAGE(s + 1, buf ^ 1);    // in-flight during compute

        if ((s & 3) == 0) {
            #pragma unroll
            for (int i = 0; i < 4; ++i)
                #pragma unroll
                for (int j = 0; j < 8; ++j) acc[i][j] = 0.f;
        }

        const float4* A4 = (const float4*)&As[buf][0];
        const float4* B4 = (const float4*)&Bs[buf][0];
        #pragma unroll 4
        for (int cl = 0; cl < 32; ++cl) {
            float4 a  = A4[cl * 16 + ra];     // rows ty*4+0..3 (broadcast)
            float4 b0 = B4[cl * 32 + rb0];    // cols tx*8+0..3
            float4 b1 = B4[cl * 32 + rb1];    // cols tx*8+4..7
            float av[4] = {a.x, a.y, a.z, a.w};
            float bv[8] = {b0.x, b0.y, b0.z, b0.w, b1.x, b1.y, b1.z, b1.w};
            #pragma unroll
            for (int i = 0; i < 4; ++i)
                #pragma unroll
                for (int j = 0; j < 8; ++j)
                    acc[i][j] = fmaf(av[i], bv[j], acc[i][j]); // c-ascending
        }

        if ((s & 3) == 3) {                   // tile complete: d2 + top-9
            const int colbase = coloct + (s >> 2) * 128;
            float4 cn0 = *(const float4*)&sqb[colbase + tx * 8];
            float4 cn1 = *(const float4*)&sqb[colbase + tx * 8 + 4];
            float cn[8] = {cn0.x, cn0.y, cn0.z, cn0.w,
                           cn1.x, cn1.y, cn1.z, cn1.w};
            #pragma unroll
            for (int i = 0; i < 4; ++i)
                #pragma unroll
                for (int j = 0; j < 8; ++j) {
                    float d2 = fmaf(-2.0f, acc[i][j], rown[i] + cn[j]);
                    if (d2 < cd[i][8])
                        insert9(cd[i], ci[i], d2, colbase + tx * 8 + j);
                }
        }
    }

    // cross-tx merge: the 16 lanes sharing ty hold disjoint column slices of
    // the same 4 rows. Butterfly over tx bits (consecutive lanes, one wave).
    #pragma unroll
    for (int m = 1; m < 16; m <<= 1) {
        #pragma unroll
        for (int i = 0; i < 4; ++i) {
            float od[9]; int oi[9];
            #pragma unroll
            for (int p = 0; p < 9; ++p) {
                od[p] = __shfl_xor(cd[i][p], m);
                oi[p] = __shfl_xor(ci[i][p], m);
            }
            #pragma unroll
            for (int p = 0; p < 9; ++p)
                if (od[p] < cd[i][8]) insert9(cd[i], ci[i], od[p], oi[p]);
        }
    }

    // partial lists: pd/pi[b][oct][k][n], single writer per row (tx==0)
    if (tx == 0) {
        #pragma unroll
        for (int i = 0; i < 4; ++i) {
            int n = rowbase + ty * 4 + i;
            #pragma unroll
            for (int k = 0; k < 9; ++k) {
                size_t o = (((size_t)b * 8 + oct) * 9 + k) * Nn + n;
                pd[o] = cd[i][k];
                pi[o] = ci[i][k];
            }
        }
    }
}

// ---------------------------------------------------------------------------
// K2b: merge the eight column-octant top-9 lists per row. Ascending octant
// order + strict-< insertion keeps lower col indices first on ties (stable).
// ---------------------------------------------------------------------------
__global__ void k_merge(const float* __restrict__ pd, const int* __restrict__ pi,
                        int* __restrict__ idxOut) {
    int id = blockIdx.x * 256 + threadIdx.x;  // 16384
    int b = id >> 12, n = id & (Nn - 1);
    float d0[9]; int i0[9];
    #pragma unroll
    for (int k = 0; k < 9; ++k) {
        size_t o = (((size_t)b * 8 + 0) * 9 + k) * Nn + n;
        d0[k] = pd[o]; i0[k] = pi[o];
    }
    #pragma unroll
    for (int q = 1; q < 8; ++q) {
        #pragma unroll
        for (int k = 0; k < 9; ++k) {
            size_t o = (((size_t)b * 8 + q) * 9 + k) * Nn + n;
            float dv = pd[o]; int iv = pi[o];
            if (dv < d0[8]) insert9(d0, i0, dv, iv);
        }
    }
    #pragma unroll
    for (int k = 0; k < 9; ++k)
        idxOut[((size_t)b * 9 + k) * Nn + n] = i0[k];
}

// ---------------------------------------------------------------------------
// K3: h0[b][c][n] = (1+eps)*x[b][c][n] + sum_k x[b][c][idx[b][k][n]]
// ---------------------------------------------------------------------------
__global__ void k_gather(const float* __restrict__ x, const int* __restrict__ idx,
                         const float* __restrict__ epsp, float* __restrict__ h0) {
    int id = blockIdx.x * 256 + threadIdx.x;          // B*C*N = 2097152
    int n  = id & (Nn - 1);
    int bc = id >> 12;                                // b*C + c
    int b  = bc >> 7;
    const float* xr = x + (size_t)bc * Nn;
    const int* ib = idx + (size_t)b * 9 * Nn + n;
    float s = (1.0f + epsp[0]) * xr[n];
    #pragma unroll
    for (int k = 0; k < 9; ++k) s += xr[ib[(size_t)k * Nn]];
    h0[id] = s;
}

// ---------------------------------------------------------------------------
// K4/K5: out[b][d][n] = act( bias[d] + sum_c W[c][d] * in[b][c][n] )
// ---------------------------------------------------------------------------
template <bool RELU>
__global__ __launch_bounds__(256, 2) void k_mlp(
        const float* __restrict__ in, const float* __restrict__ W,
        const float* __restrict__ bias, float* __restrict__ out) {
    const int t  = threadIdx.x;
    const int td = t & 15;
    const int tn = t >> 4;
    const int bid = blockIdx.x;   // B*2*64 = 512
    const int b = bid >> 7;
    const int dbase = ((bid >> 6) & 1) * 64;
    const int nb = (bid & 63) * 64;

    __shared__ alignas(16) float Ws[128 * 64];
    __shared__ alignas(16) float Hs[128 * 64];

    for (int k = t; k < 128 * 64; k += 256) {
        int i = k & 63; int c = k >> 6;
        int sw = c * 64 + ((((i >> 2) ^ (c & 7)) << 2) | (i & 3));
        Ws[sw] = W[c * 128 + dbase + i];
        Hs[sw] = in[((size_t)b * 128 + c) * Nn + nb + i];
    }
    __syncthreads();

    float acc[4][4];
    #pragma unroll
    for (int dd = 0; dd < 4; ++dd)
        #pragma unroll
        for (int nn = 0; nn < 4; ++nn) acc[dd][nn] = 0.f;

    const float4* W4 = reinterpret_cast<const float4*>(Ws);
    const float4* H4 = reinterpret_cast<const float4*>(Hs);
    for (int c = 0; c < 128; ++c) {
        int cx = c & 7;
        float4 w = W4[c * 16 + (td ^ cx)];
        float4 h = H4[c * 16 + (tn ^ cx)];
        float wf[4] = {w.x, w.y, w.z, w.w};
        float hf[4] = {h.x, h.y, h.z, h.w};
        #pragma unroll
        for (int dd = 0; dd < 4; ++dd)
            #pragma unroll
            for (int nn = 0; nn < 4; ++nn)
                acc[dd][nn] = fmaf(wf[dd], hf[nn], acc[dd][nn]);
    }

    #pragma unroll
    for (int dd = 0; dd < 4; ++dd) {
        int d = dbase + 4 * td + dd;
        float bb = bias[d];
        float4 o;
        o.x = acc[dd][0] + bb; o.y = acc[dd][1] + bb;
        o.z = acc[dd][2] + bb; o.w = acc[dd][3] + bb;
        if (RELU) {
            o.x = fmaxf(o.x, 0.f); o.y = fmaxf(o.y, 0.f);
            o.z = fmaxf(o.z, 0.f); o.w = fmaxf(o.w, 0.f);
        }
        *reinterpret_cast<float4*>(&out[((size_t)b * 128 + d) * Nn + nb + 4 * tn]) = o;
    }
}

// ---------------------------------------------------------------------------
// K6: per-channel batch-norm stats (biased var), 1 block per channel.
// ---------------------------------------------------------------------------
__global__ void k_bnstats(const float* __restrict__ o, const float* __restrict__ gamma,
                          const float* __restrict__ beta, float* __restrict__ scsh) {
    int e = blockIdx.x, t = threadIdx.x;
    float s = 0.f, s2 = 0.f;
    for (int b = 0; b < Bc; ++b) {
        const float* p = o + ((size_t)b * 128 + e) * Nn;
        for (int n = t; n < Nn; n += 256) {
            float v = p[n];
            s += v;
            s2 = fmaf(v, v, s2);
        }
    }
    __shared__ float rs[256], rq[256];
    rs[t] = s; rq[t] = s2;
    __syncthreads();
    for (int off = 128; off > 0; off >>= 1) {
        if (t < off) { rs[t] += rs[t + off]; rq[t] += rq[t + off]; }
        __syncthreads();
    }
    if (t == 0) {
        float mean = rs[0] * (1.0f / 16384.0f);
        float var  = rq[0] * (1.0f / 16384.0f) - mean * mean;
        if (var < 0.f) var = 0.f;
        float sc = gamma[e] * rsqrtf(var + 1e-5f);
        scsh[e] = sc;
        scsh[128 + e] = beta[e] - mean * sc;
    }
}

// ---------------------------------------------------------------------------
// K7: out = relu(scale[e]*o + shift[e] + x), in place on d_out, float4.
// ---------------------------------------------------------------------------
__global__ void k_bnapply(float* __restrict__ o, const float* __restrict__ x,
                          const float* __restrict__ scsh) {
    int id4 = blockIdx.x * 256 + threadIdx.x;         // 524288
    int e = (id4 >> 10) & 127;
    float sc = scsh[e], sh = scsh[128 + e];
    float4 v = reinterpret_cast<const float4*>(o)[id4];
    float4 r = reinterpret_cast<const float4*>(x)[id4];
    float4 w;
    w.x = fmaxf(fmaf(sc, v.x, sh) + r.x, 0.f);
    w.y = fmaxf(fmaf(sc, v.y, sh) + r.y, 0.f);
    w.z = fmaxf(fmaf(sc, v.z, sh) + r.z, 0.f);
    w.w = fmaxf(fmaf(sc, v.w, sh) + r.w, 0.f);
    reinterpret_cast<float4*>(o)[id4] = w;
}

// ---------------------------------------------------------------------------
extern "C" void kernel_launch(void* const* d_in, const int* in_sizes, int n_in,
                              void* d_out, int out_size, void* d_ws, size_t ws_size,
                              hipStream_t stream) {
    const float* x     = (const float*)d_in[0];
    const float* epsp  = (const float*)d_in[1];
    const float* W1    = (const float*)d_in[2];
    const float* b1    = (const float*)d_in[3];
    const float* W2    = (const float*)d_in[4];
    const float* b2    = (const float*)d_in[5];
    const float* gamma = (const float*)d_in[6];
    const float* beta  = (const float*)d_in[7];
    float* out = (float*)d_out;

    // workspace (floats): sq[16384] | idx[147456] | h0[2097152] | h1[2097152]
    // | scsh[256]  (~17.4 MB). pd aliases h0, pi aliases h1 (each
    // [4][8][9][4096] = 1179648 elems <= 2097152): both consumed by k_merge
    // BEFORE k_gather writes h0 and k_mlp<true> writes h1.
    float* ws   = (float*)d_ws;
    float* sq   = ws;
    int*   idx  = (int*)(ws + 16384);
    float* h0   = ws + 16384 + (size_t)Bc * 9 * Nn;
    float* h1   = h0 + (size_t)Bc * Cc * Nn;
    float* scsh = h1 + (size_t)Bc * Cc * Nn;
    float* pd   = h0;                          // [4][8][9][4096]
    int*   pi   = (int*)h1;                    // [4][8][9][4096]

    k_sq        <<<64,   256, 0, stream>>>(x, sq);
    k_gram_topk <<<2048, 256, 0, stream>>>(x, sq, pd, pi);
    k_merge     <<<64,   256, 0, stream>>>(pd, pi, idx);
    k_gather    <<<8192, 256, 0, stream>>>(x, idx, epsp, h0);
    k_mlp<true> <<<512,  256, 0, stream>>>(h0, W1, b1, h1);
    k_mlp<false><<<512,  256, 0, stream>>>(h1, W2, b2, out);
    k_bnstats   <<<128,  256, 0, stream>>>(out, gamma, beta, scsh);
    k_bnapply   <<<2048, 256, 0, stream>>>(out, x, scsh);
}